// Round 2
// baseline (293.120 us; speedup 1.0000x reference)
//
#include <hip/hip_runtime.h>
#include <stdint.h>

#define K_ANCH 131072
#define G_BOX  256
#define NPOS_TGT 128
#define NSAMPLE 256
#define POS_CAP 8192
#define NEG_CAP 32768

// ---------------- Threefry-2x32-20 (JAX-compatible) ----------------
struct TF2 { uint32_t a, b; };

__host__ __device__ constexpr uint32_t rotl32(uint32_t v, int d) {
  return (v << d) | (v >> (32 - d));
}

__host__ __device__ constexpr TF2 threefry(uint32_t k0, uint32_t k1,
                                           uint32_t x0, uint32_t x1) {
  const uint32_t ks0 = k0, ks1 = k1, ks2 = k0 ^ k1 ^ 0x1BD11BDAu;
  const int R0[4] = {13, 15, 26, 6};
  const int R1[4] = {17, 29, 16, 24};
  x0 += ks0; x1 += ks1;
  for (int r = 0; r < 4; ++r) { x0 += x1; x1 = rotl32(x1, R0[r]); x1 ^= x0; }
  x0 += ks1; x1 += ks2 + 1u;
  for (int r = 0; r < 4; ++r) { x0 += x1; x1 = rotl32(x1, R1[r]); x1 ^= x0; }
  x0 += ks2; x1 += ks0 + 2u;
  for (int r = 0; r < 4; ++r) { x0 += x1; x1 = rotl32(x1, R0[r]); x1 ^= x0; }
  x0 += ks0; x1 += ks1 + 3u;
  for (int r = 0; r < 4; ++r) { x0 += x1; x1 = rotl32(x1, R1[r]); x1 ^= x0; }
  x0 += ks1; x1 += ks2 + 4u;
  for (int r = 0; r < 4; ++r) { x0 += x1; x1 = rotl32(x1, R0[r]); x1 ^= x0; }
  x0 += ks2; x1 += ks0 + 5u;
  return TF2{x0, x1};
}

// jax.random.key(42) -> (0, 42). partitionable (default since jax 0.4.30):
//   split: key_i = cipher(key, (0, i))
//   random_bits(32): bits_i = cipher(key, (0, i)).a ^ .b
constexpr TF2 KPOS = threefry(0u, 42u, 0u, 0u);  // k1 -> p_pos
constexpr TF2 KNEG = threefry(0u, 42u, 0u, 1u);  // k2 -> p_neg

__device__ __forceinline__ uint32_t rbits(TF2 k, uint32_t i) {
  TF2 r = threefry(k.a, k.b, 0u, i);
  return r.a ^ r.b;
}

__device__ __forceinline__ float p_from_bits(uint32_t bits) {
  uint32_t fb = 0x3f800000u | (bits >> 9);
  float f = __uint_as_float(fb) - 1.0f;
  return fmaxf(f, 0.0f);  // jax: lax.max(minval, ...)
}

__device__ __forceinline__ uint64_t prio_key(float p, uint32_t idx) {
  return ((uint64_t)__float_as_uint(p) << 32) | (uint64_t)idx;  // smaller = earlier rank (stable)
}

// ---------------- IoU (bitwise-matched to reference) ----------------
__device__ __forceinline__ float iou_one(float4 a, float4 b) {
  #pragma clang fp contract(off)
  float tlx = fmaxf(a.x, b.x), tly = fmaxf(a.y, b.y);
  float brx = fminf(a.z, b.z), bry = fminf(a.w, b.w);
  float w = brx - tlx, h = bry - tly;
  float flag = (tlx < brx && tly < bry) ? 1.0f : 0.0f;
  float inter = w * h * flag;
  float area_a = (a.z - a.x) * (a.w - a.y);
  float area_b = (b.z - b.x) * (b.w - b.y);
  float u = (area_a + area_b) - inter;
  float r = inter / u;
  return fmaxf(r, 0.0f);  // canonicalize -0 -> +0 (comparisons unchanged)
}

struct ScalarBlk {
  unsigned long long cutoff[2];  // [pos, neg]; keep key iff key < cutoff
  int B_pos, r_pos, B_neg, r_neg;
  int do_pos, do_neg, pos_kept, pad;
};

// K1: per-anchor max/argmax over gts + initial label
__global__ __launch_bounds__(256) void k_anchor(const float4* __restrict__ anchor,
                                                const float4* __restrict__ bbox,
                                                int* __restrict__ argmax,
                                                int* __restrict__ label) {
  __shared__ float4 gts[G_BOX];
  int tid = threadIdx.x;
  gts[tid] = bbox[tid];
  __syncthreads();
  int i = blockIdx.x * 256 + tid;
  float4 a = anchor[i];
  float best = -1.0f; int bidx = 0;
  for (int g = 0; g < G_BOX; ++g) {
    float v = iou_one(a, gts[g]);
    if (v > best) { best = v; bidx = g; }  // first-max like jnp.argmax
  }
  argmax[i] = bidx;
  int lbl = -1;
  if (best < 0.3f) lbl = 0;
  if (best >= 0.7f) lbl = 1;
  label[i] = lbl;
}

// K2: per-gt argmax over anchors (first max index)
__global__ __launch_bounds__(256) void k_gt(const float4* __restrict__ anchor,
                                            const float4* __restrict__ bbox,
                                            int* __restrict__ gt_argmax) {
  __shared__ uint64_t red[256];
  int g = blockIdx.x;
  float4 b = bbox[g];
  int tid = threadIdx.x;
  uint64_t best = 0;
  for (int i = tid; i < K_ANCH; i += 256) {
    float v = iou_one(anchor[i], b);
    uint64_t key = ((uint64_t)__float_as_uint(v) << 32) | (uint64_t)(~(uint32_t)i);
    best = key > best ? key : best;
  }
  red[tid] = best;
  __syncthreads();
  for (int s = 128; s > 0; s >>= 1) {
    if (tid < s) { uint64_t o = red[tid + s]; if (o > red[tid]) red[tid] = o; }
    __syncthreads();
  }
  if (tid == 0) gt_argmax[g] = (int)(~(uint32_t)red[0]);
}

// K3: force gt-best anchors: label=1, argmax=g (sequential last-wins like scatter)
__global__ void k_force(const int* __restrict__ gt_argmax,
                        int* __restrict__ argmax, int* __restrict__ label) {
  __shared__ int ga[G_BOX];
  int tid = threadIdx.x;
  ga[tid] = gt_argmax[tid];
  __syncthreads();
  label[ga[tid]] = 1;
  if (tid == 0) {
    for (int t = 0; t < G_BOX; ++t) argmax[ga[t]] = t;
  }
}

// K4: histogram of priorities over 1024 buckets, per class
__global__ __launch_bounds__(256) void k_hist(const int* __restrict__ label,
                                              uint32_t* __restrict__ hist) {
  int i = blockIdx.x * 256 + threadIdx.x;
  int lbl = label[i];
  if (lbl < 0) return;
  TF2 k = (lbl == 1) ? KPOS : KNEG;
  float p = p_from_bits(rbits(k, (uint32_t)i));
  int b = (int)(p * 1024.0f); if (b > 1023) b = 1023;
  atomicAdd((unsigned int*)&hist[(lbl == 1 ? 0 : 1024) + b], 1u);
}

// K5: find boundary bucket + in-bucket rank for pos and neg
__global__ __launch_bounds__(256) void k_select(const uint32_t* __restrict__ hist,
                                                ScalarBlk* __restrict__ sc) {
  __shared__ uint32_t h[2048];
  for (int t = threadIdx.x; t < 2048; t += 256) h[t] = hist[t];
  __syncthreads();
  if (threadIdx.x != 0) return;
  uint32_t total_pos = 0, total_neg = 0;
  for (int b = 0; b < 1024; ++b) total_pos += h[b];
  for (int b = 0; b < 1024; ++b) total_neg += h[1024 + b];
  int pos_kept = total_pos < (uint32_t)NPOS_TGT ? (int)total_pos : NPOS_TGT;
  int n_neg = NSAMPLE - pos_kept;
  sc->pos_kept = pos_kept;
  if (total_pos <= (uint32_t)NPOS_TGT) {
    sc->do_pos = 0; sc->cutoff[0] = ~0ull;
  } else {
    uint32_t cum = 0; int B = 0;
    for (; B < 1024; ++B) { if (cum + h[B] > (uint32_t)NPOS_TGT) break; cum += h[B]; }
    sc->do_pos = 1; sc->B_pos = B; sc->r_pos = NPOS_TGT - (int)cum;
  }
  if (total_neg <= (uint32_t)n_neg) {
    sc->do_neg = 0; sc->cutoff[1] = ~0ull;
  } else {
    uint32_t cum = 0; int B = 0;
    for (; B < 1024; ++B) { if (cum + h[1024 + B] > (uint32_t)n_neg) break; cum += h[1024 + B]; }
    sc->do_neg = 1; sc->B_neg = B; sc->r_neg = n_neg - (int)cum;
  }
}

// K6: collect boundary-bucket members
__global__ __launch_bounds__(256) void k_collect(const int* __restrict__ label,
                                                 uint64_t* __restrict__ pos_list,
                                                 uint64_t* __restrict__ neg_list,
                                                 uint32_t* __restrict__ counters,
                                                 const ScalarBlk* __restrict__ sc) {
  int i = blockIdx.x * 256 + threadIdx.x;
  int lbl = label[i];
  if (lbl < 0) return;
  if (lbl == 1) {
    if (!sc->do_pos) return;
    float p = p_from_bits(rbits(KPOS, (uint32_t)i));
    int b = (int)(p * 1024.0f); if (b > 1023) b = 1023;
    if (b != sc->B_pos) return;
    uint32_t slot = atomicAdd((unsigned int*)&counters[0], 1u);
    if (slot < POS_CAP) pos_list[slot] = prio_key(p, (uint32_t)i);
  } else {
    if (!sc->do_neg) return;
    float p = p_from_bits(rbits(KNEG, (uint32_t)i));
    int b = (int)(p * 1024.0f); if (b > 1023) b = 1023;
    if (b != sc->B_neg) return;
    uint32_t slot = atomicAdd((unsigned int*)&counters[1], 1u);
    if (slot < NEG_CAP) neg_list[slot] = prio_key(p, (uint32_t)i);
  }
}

// K7: exact r-th smallest key within boundary bucket -> cutoff
__global__ __launch_bounds__(256) void k_cutoff(const uint64_t* __restrict__ pos_list,
                                                const uint64_t* __restrict__ neg_list,
                                                const uint32_t* __restrict__ counters,
                                                ScalarBlk* __restrict__ sc) {
  int cls = blockIdx.x;
  int doit = (cls == 0) ? sc->do_pos : sc->do_neg;
  if (!doit) return;
  const uint64_t* list = (cls == 0) ? pos_list : neg_list;
  int cap = (cls == 0) ? POS_CAP : NEG_CAP;
  int m = (int)counters[cls]; if (m > cap) m = cap;
  int r = (cls == 0) ? sc->r_pos : sc->r_neg;
  for (int j = threadIdx.x; j < m; j += 256) {
    uint64_t kj = list[j];
    int rank = 0;
    for (int t = 0; t < m; ++t) rank += (list[t] < kj) ? 1 : 0;
    if (rank == r) sc->cutoff[cls] = (unsigned long long)kj;
  }
}

// K8: final labels + bbox2loc
__global__ __launch_bounds__(256) void k_final(const float4* __restrict__ anchor,
                                               const float4* __restrict__ bbox,
                                               const int* __restrict__ argmax,
                                               const int* __restrict__ label,
                                               const ScalarBlk* __restrict__ sc,
                                               float* __restrict__ out) {
  #pragma clang fp contract(off)
  int i = blockIdx.x * 256 + threadIdx.x;
  int lbl = label[i];
  if (lbl == 1) {
    float p = p_from_bits(rbits(KPOS, (uint32_t)i));
    if (prio_key(p, (uint32_t)i) >= sc->cutoff[0]) lbl = -1;
  } else if (lbl == 0) {
    float p = p_from_bits(rbits(KNEG, (uint32_t)i));
    if (prio_key(p, (uint32_t)i) >= sc->cutoff[1]) lbl = -1;
  }
  out[K_ANCH * 4 + i] = (float)lbl;

  float4 a = anchor[i];
  float4 b = bbox[argmax[i]];
  const float eps = 1.1920928955078125e-07f;
  float w  = fmaxf(a.z - a.x, eps);
  float h  = fmaxf(a.w - a.y, eps);
  float cx = a.x + 0.5f * (a.z - a.x);
  float cy = a.y + 0.5f * (a.w - a.y);
  float bw = b.z - b.x, bh = b.w - b.y;
  float bcx = b.x + 0.5f * bw, bcy = b.y + 0.5f * bh;
  float dx = (bcx - cx) / w, dy = (bcy - cy) / h;
  float dw = logf(bw / w), dh = logf(bh / h);
  float4 o;
  if (sc->pos_kept > 0) o = make_float4(dx, dy, dw, dh);
  else o = make_float4(0.f, 0.f, 0.f, 0.f);
  ((float4*)out)[i] = o;
}

extern "C" void kernel_launch(void* const* d_in, const int* in_sizes, int n_in,
                              void* d_out, int out_size, void* d_ws, size_t ws_size,
                              hipStream_t stream) {
  const float4* anchor = (const float4*)d_in[0];
  const float4* bbox   = (const float4*)d_in[1];
  char* ws = (char*)d_ws;

  uint32_t* hist     = (uint32_t*)(ws);                 // 2048 * 4 = 8192 B
  uint32_t* counters = (uint32_t*)(ws + 8192);          // 8 B
  ScalarBlk* sc      = (ScalarBlk*)(ws + 8256);
  int* gt_argmax     = (int*)(ws + 8320);               // 1 KB
  int* argmax        = (int*)(ws + 16384);              // 512 KB
  int* label         = (int*)(ws + 16384 + 524288);     // 512 KB
  uint64_t* pos_list = (uint64_t*)(ws + 16384 + 1048576);
  uint64_t* neg_list = pos_list + POS_CAP;

  hipMemsetAsync(ws, 0, 8256, stream);  // hist + counters
  k_anchor <<<512, 256, 0, stream>>>(anchor, bbox, argmax, label);
  k_gt     <<<256, 256, 0, stream>>>(anchor, bbox, gt_argmax);
  k_force  <<<1,   256, 0, stream>>>(gt_argmax, argmax, label);
  k_hist   <<<512, 256, 0, stream>>>(label, hist);
  k_select <<<1,   256, 0, stream>>>(hist, sc);
  k_collect<<<512, 256, 0, stream>>>(label, pos_list, neg_list, counters, sc);
  k_cutoff <<<2,   256, 0, stream>>>(pos_list, neg_list, counters, sc);
  k_final  <<<512, 256, 0, stream>>>(anchor, bbox, argmax, label, sc, (float*)d_out);
}

// Round 3
// 172.106 us; speedup vs baseline: 1.7031x; 1.7031x over previous
//
#include <hip/hip_runtime.h>
#include <stdint.h>

#define K_ANCH 131072
#define G_BOX  256
#define NPOS_TGT 128
#define NSAMPLE 256
#define POS_CAP 8192
#define NEG_CAP 32768

// ---------------- Threefry-2x32-20 (JAX-compatible) ----------------
struct TF2 { uint32_t a, b; };

__host__ __device__ constexpr uint32_t rotl32(uint32_t v, int d) {
  return (v << d) | (v >> (32 - d));
}

__host__ __device__ constexpr TF2 threefry(uint32_t k0, uint32_t k1,
                                           uint32_t x0, uint32_t x1) {
  const uint32_t ks0 = k0, ks1 = k1, ks2 = k0 ^ k1 ^ 0x1BD11BDAu;
  const int R0[4] = {13, 15, 26, 6};
  const int R1[4] = {17, 29, 16, 24};
  x0 += ks0; x1 += ks1;
  for (int r = 0; r < 4; ++r) { x0 += x1; x1 = rotl32(x1, R0[r]); x1 ^= x0; }
  x0 += ks1; x1 += ks2 + 1u;
  for (int r = 0; r < 4; ++r) { x0 += x1; x1 = rotl32(x1, R1[r]); x1 ^= x0; }
  x0 += ks2; x1 += ks0 + 2u;
  for (int r = 0; r < 4; ++r) { x0 += x1; x1 = rotl32(x1, R0[r]); x1 ^= x0; }
  x0 += ks0; x1 += ks1 + 3u;
  for (int r = 0; r < 4; ++r) { x0 += x1; x1 = rotl32(x1, R1[r]); x1 ^= x0; }
  x0 += ks1; x1 += ks2 + 4u;
  for (int r = 0; r < 4; ++r) { x0 += x1; x1 = rotl32(x1, R0[r]); x1 ^= x0; }
  x0 += ks2; x1 += ks0 + 5u;
  return TF2{x0, x1};
}

constexpr TF2 KPOS = threefry(0u, 42u, 0u, 0u);  // k1 -> p_pos
constexpr TF2 KNEG = threefry(0u, 42u, 0u, 1u);  // k2 -> p_neg

__device__ __forceinline__ uint32_t rbits(TF2 k, uint32_t i) {
  TF2 r = threefry(k.a, k.b, 0u, i);
  return r.a ^ r.b;
}

__device__ __forceinline__ float p_from_bits(uint32_t bits) {
  uint32_t fb = 0x3f800000u | (bits >> 9);
  float f = __uint_as_float(fb) - 1.0f;
  return fmaxf(f, 0.0f);
}

__device__ __forceinline__ uint64_t prio_key(float p, uint32_t idx) {
  return ((uint64_t)__float_as_uint(p) << 32) | (uint64_t)idx;
}

// ---------------- IoU (bitwise-matched to reference) ----------------
__device__ __forceinline__ float iou_one(float4 a, float4 b) {
  #pragma clang fp contract(off)
  float tlx = fmaxf(a.x, b.x), tly = fmaxf(a.y, b.y);
  float brx = fminf(a.z, b.z), bry = fminf(a.w, b.w);
  float w = brx - tlx, h = bry - tly;
  float flag = (tlx < brx && tly < bry) ? 1.0f : 0.0f;
  float inter = w * h * flag;
  float area_a = (a.z - a.x) * (a.w - a.y);
  float area_b = (b.z - b.x) * (b.w - b.y);
  float u = (area_a + area_b) - inter;
  float r = inter / u;
  return fmaxf(r, 0.0f);
}

struct ScalarBlk {
  unsigned long long cutoff[2];
  int B_pos, r_pos, B_neg, r_neg;
  int do_pos, do_neg, pos_kept, pad;
};

// K1: per-anchor max/argmax over gts + initial label
__global__ __launch_bounds__(256) void k_anchor(const float4* __restrict__ anchor,
                                                const float4* __restrict__ bbox,
                                                int* __restrict__ argmax,
                                                int* __restrict__ label) {
  __shared__ float4 gts[G_BOX];
  int tid = threadIdx.x;
  gts[tid] = bbox[tid];
  __syncthreads();
  int i = blockIdx.x * 256 + tid;
  float4 a = anchor[i];
  float best = -1.0f; int bidx = 0;
  for (int g = 0; g < G_BOX; ++g) {
    float v = iou_one(a, gts[g]);
    if (v > best) { best = v; bidx = g; }  // first-max like jnp.argmax
  }
  argmax[i] = bidx;
  int lbl = -1;
  if (best < 0.3f) lbl = 0;
  if (best >= 0.7f) lbl = 1;
  label[i] = lbl;
}

// K2: per-gt partial max over a 256-anchor chunk (LDS-staged), atomicMax combine.
// Latency-bound fix: old k_gt was 1 wave/SIMD with serial global loads (168us).
__global__ __launch_bounds__(256) void k_gt_partial(const float4* __restrict__ anchor,
                                                    const float4* __restrict__ bbox,
                                                    unsigned long long* __restrict__ gkey) {
  __shared__ float4 la[256];
  int tid = threadIdx.x;
  int base = blockIdx.x * 256;
  la[tid] = anchor[base + tid];
  float4 b = bbox[tid];  // thread owns gt g = tid
  __syncthreads();
  unsigned long long best = 0;
  #pragma unroll 4
  for (int t = 0; t < 256; ++t) {
    float v = iou_one(la[t], b);  // LDS broadcast read, conflict-free
    unsigned long long key =
        ((unsigned long long)__float_as_uint(v) << 32) |
        (unsigned long long)(~(uint32_t)(base + t));  // max -> smallest idx on tie
    best = key > best ? key : best;
  }
  atomicMax(&gkey[tid], best);  // order-independent, replay-safe
}

// K3: force gt-best anchors: label=1, argmax=g (sequential last-wins like scatter)
__global__ void k_force(const unsigned long long* __restrict__ gkey,
                        int* __restrict__ argmax, int* __restrict__ label) {
  __shared__ int ga[G_BOX];
  int tid = threadIdx.x;
  ga[tid] = (int)(~(uint32_t)(gkey[tid] & 0xffffffffull));
  __syncthreads();
  label[ga[tid]] = 1;
  if (tid == 0) {
    for (int t = 0; t < G_BOX; ++t) argmax[ga[t]] = t;
  }
}

// K4: histogram of priorities over 1024 buckets, per class
__global__ __launch_bounds__(256) void k_hist(const int* __restrict__ label,
                                              uint32_t* __restrict__ hist) {
  int i = blockIdx.x * 256 + threadIdx.x;
  int lbl = label[i];
  if (lbl < 0) return;
  TF2 k = (lbl == 1) ? KPOS : KNEG;
  float p = p_from_bits(rbits(k, (uint32_t)i));
  int b = (int)(p * 1024.0f); if (b > 1023) b = 1023;
  atomicAdd((unsigned int*)&hist[(lbl == 1 ? 0 : 1024) + b], 1u);
}

// K5: find boundary bucket + in-bucket rank for pos and neg
__global__ __launch_bounds__(256) void k_select(const uint32_t* __restrict__ hist,
                                                ScalarBlk* __restrict__ sc) {
  __shared__ uint32_t h[2048];
  for (int t = threadIdx.x; t < 2048; t += 256) h[t] = hist[t];
  __syncthreads();
  if (threadIdx.x != 0) return;
  uint32_t total_pos = 0, total_neg = 0;
  for (int b = 0; b < 1024; ++b) total_pos += h[b];
  for (int b = 0; b < 1024; ++b) total_neg += h[1024 + b];
  int pos_kept = total_pos < (uint32_t)NPOS_TGT ? (int)total_pos : NPOS_TGT;
  int n_neg = NSAMPLE - pos_kept;
  sc->pos_kept = pos_kept;
  if (total_pos <= (uint32_t)NPOS_TGT) {
    sc->do_pos = 0; sc->cutoff[0] = ~0ull;
  } else {
    uint32_t cum = 0; int B = 0;
    for (; B < 1024; ++B) { if (cum + h[B] > (uint32_t)NPOS_TGT) break; cum += h[B]; }
    sc->do_pos = 1; sc->B_pos = B; sc->r_pos = NPOS_TGT - (int)cum;
  }
  if (total_neg <= (uint32_t)n_neg) {
    sc->do_neg = 0; sc->cutoff[1] = ~0ull;
  } else {
    uint32_t cum = 0; int B = 0;
    for (; B < 1024; ++B) { if (cum + h[1024 + B] > (uint32_t)n_neg) break; cum += h[1024 + B]; }
    sc->do_neg = 1; sc->B_neg = B; sc->r_neg = n_neg - (int)cum;
  }
}

// K6: collect boundary-bucket members
__global__ __launch_bounds__(256) void k_collect(const int* __restrict__ label,
                                                 uint64_t* __restrict__ pos_list,
                                                 uint64_t* __restrict__ neg_list,
                                                 uint32_t* __restrict__ counters,
                                                 const ScalarBlk* __restrict__ sc) {
  int i = blockIdx.x * 256 + threadIdx.x;
  int lbl = label[i];
  if (lbl < 0) return;
  if (lbl == 1) {
    if (!sc->do_pos) return;
    float p = p_from_bits(rbits(KPOS, (uint32_t)i));
    int b = (int)(p * 1024.0f); if (b > 1023) b = 1023;
    if (b != sc->B_pos) return;
    uint32_t slot = atomicAdd((unsigned int*)&counters[0], 1u);
    if (slot < POS_CAP) pos_list[slot] = prio_key(p, (uint32_t)i);
  } else {
    if (!sc->do_neg) return;
    float p = p_from_bits(rbits(KNEG, (uint32_t)i));
    int b = (int)(p * 1024.0f); if (b > 1023) b = 1023;
    if (b != sc->B_neg) return;
    uint32_t slot = atomicAdd((unsigned int*)&counters[1], 1u);
    if (slot < NEG_CAP) neg_list[slot] = prio_key(p, (uint32_t)i);
  }
}

// K7: exact r-th smallest key within boundary bucket -> cutoff
__global__ __launch_bounds__(256) void k_cutoff(const uint64_t* __restrict__ pos_list,
                                                const uint64_t* __restrict__ neg_list,
                                                const uint32_t* __restrict__ counters,
                                                ScalarBlk* __restrict__ sc) {
  int cls = blockIdx.x;
  int doit = (cls == 0) ? sc->do_pos : sc->do_neg;
  if (!doit) return;
  const uint64_t* list = (cls == 0) ? pos_list : neg_list;
  int cap = (cls == 0) ? POS_CAP : NEG_CAP;
  int m = (int)counters[cls]; if (m > cap) m = cap;
  int r = (cls == 0) ? sc->r_pos : sc->r_neg;
  for (int j = threadIdx.x; j < m; j += 256) {
    uint64_t kj = list[j];
    int rank = 0;
    for (int t = 0; t < m; ++t) rank += (list[t] < kj) ? 1 : 0;
    if (rank == r) sc->cutoff[cls] = (unsigned long long)kj;
  }
}

// K8: final labels + bbox2loc
__global__ __launch_bounds__(256) void k_final(const float4* __restrict__ anchor,
                                               const float4* __restrict__ bbox,
                                               const int* __restrict__ argmax,
                                               const int* __restrict__ label,
                                               const ScalarBlk* __restrict__ sc,
                                               float* __restrict__ out) {
  #pragma clang fp contract(off)
  int i = blockIdx.x * 256 + threadIdx.x;
  int lbl = label[i];
  if (lbl == 1) {
    float p = p_from_bits(rbits(KPOS, (uint32_t)i));
    if (prio_key(p, (uint32_t)i) >= sc->cutoff[0]) lbl = -1;
  } else if (lbl == 0) {
    float p = p_from_bits(rbits(KNEG, (uint32_t)i));
    if (prio_key(p, (uint32_t)i) >= sc->cutoff[1]) lbl = -1;
  }
  out[K_ANCH * 4 + i] = (float)lbl;

  float4 a = anchor[i];
  float4 b = bbox[argmax[i]];
  const float eps = 1.1920928955078125e-07f;
  float w  = fmaxf(a.z - a.x, eps);
  float h  = fmaxf(a.w - a.y, eps);
  float cx = a.x + 0.5f * (a.z - a.x);
  float cy = a.y + 0.5f * (a.w - a.y);
  float bw = b.z - b.x, bh = b.w - b.y;
  float bcx = b.x + 0.5f * bw, bcy = b.y + 0.5f * bh;
  float dx = (bcx - cx) / w, dy = (bcy - cy) / h;
  float dw = logf(bw / w), dh = logf(bh / h);
  float4 o;
  if (sc->pos_kept > 0) o = make_float4(dx, dy, dw, dh);
  else o = make_float4(0.f, 0.f, 0.f, 0.f);
  ((float4*)out)[i] = o;
}

extern "C" void kernel_launch(void* const* d_in, const int* in_sizes, int n_in,
                              void* d_out, int out_size, void* d_ws, size_t ws_size,
                              hipStream_t stream) {
  const float4* anchor = (const float4*)d_in[0];
  const float4* bbox   = (const float4*)d_in[1];
  char* ws = (char*)d_ws;

  uint32_t* hist     = (uint32_t*)(ws);                   // [0, 8192)
  uint32_t* counters = (uint32_t*)(ws + 8192);            // [8192, 8200)
  unsigned long long* gkey = (unsigned long long*)(ws + 8704);  // [8704, 10752)
  ScalarBlk* sc      = (ScalarBlk*)(ws + 10752);
  int* argmax        = (int*)(ws + 16384);                // 512 KB
  int* label         = (int*)(ws + 16384 + 524288);       // 512 KB
  uint64_t* pos_list = (uint64_t*)(ws + 16384 + 1048576);
  uint64_t* neg_list = pos_list + POS_CAP;

  hipMemsetAsync(ws, 0, 10752, stream);  // hist + counters + gkey
  k_anchor    <<<512, 256, 0, stream>>>(anchor, bbox, argmax, label);
  k_gt_partial<<<512, 256, 0, stream>>>(anchor, bbox, gkey);
  k_force     <<<1,   256, 0, stream>>>(gkey, argmax, label);
  k_hist      <<<512, 256, 0, stream>>>(label, hist);
  k_select    <<<1,   256, 0, stream>>>(hist, sc);
  k_collect   <<<512, 256, 0, stream>>>(label, pos_list, neg_list, counters, sc);
  k_cutoff    <<<2,   256, 0, stream>>>(pos_list, neg_list, counters, sc);
  k_final     <<<512, 256, 0, stream>>>(anchor, bbox, argmax, label, sc, (float*)d_out);
}

// Round 5
// 151.949 us; speedup vs baseline: 1.9291x; 1.1327x over previous
//
#include <hip/hip_runtime.h>
#include <stdint.h>

#define K_ANCH 131072
#define G_BOX  256
#define NPOS_TGT 128
#define NSAMPLE 256
#define POS_CAP 8192
#define NEG_CAP 32768

// ---------------- Threefry-2x32-20 (JAX-compatible) ----------------
struct TF2 { uint32_t a, b; };

__host__ __device__ constexpr uint32_t rotl32(uint32_t v, int d) {
  return (v << d) | (v >> (32 - d));
}

__host__ __device__ constexpr TF2 threefry(uint32_t k0, uint32_t k1,
                                           uint32_t x0, uint32_t x1) {
  const uint32_t ks0 = k0, ks1 = k1, ks2 = k0 ^ k1 ^ 0x1BD11BDAu;
  const int R0[4] = {13, 15, 26, 6};
  const int R1[4] = {17, 29, 16, 24};
  x0 += ks0; x1 += ks1;
  for (int r = 0; r < 4; ++r) { x0 += x1; x1 = rotl32(x1, R0[r]); x1 ^= x0; }
  x0 += ks1; x1 += ks2 + 1u;
  for (int r = 0; r < 4; ++r) { x0 += x1; x1 = rotl32(x1, R1[r]); x1 ^= x0; }
  x0 += ks2; x1 += ks0 + 2u;
  for (int r = 0; r < 4; ++r) { x0 += x1; x1 = rotl32(x1, R0[r]); x1 ^= x0; }
  x0 += ks0; x1 += ks1 + 3u;
  for (int r = 0; r < 4; ++r) { x0 += x1; x1 = rotl32(x1, R1[r]); x1 ^= x0; }
  x0 += ks1; x1 += ks2 + 4u;
  for (int r = 0; r < 4; ++r) { x0 += x1; x1 = rotl32(x1, R0[r]); x1 ^= x0; }
  x0 += ks2; x1 += ks0 + 5u;
  return TF2{x0, x1};
}

constexpr TF2 KPOS = threefry(0u, 42u, 0u, 0u);  // k1 -> p_pos
constexpr TF2 KNEG = threefry(0u, 42u, 0u, 1u);  // k2 -> p_neg

__device__ __forceinline__ uint32_t rbits(TF2 k, uint32_t i) {
  TF2 r = threefry(k.a, k.b, 0u, i);
  return r.a ^ r.b;
}

__device__ __forceinline__ float p_from_bits(uint32_t bits) {
  uint32_t fb = 0x3f800000u | (bits >> 9);
  float f = __uint_as_float(fb) - 1.0f;
  return fmaxf(f, 0.0f);
}

__device__ __forceinline__ uint64_t prio_key(float p, uint32_t idx) {
  return ((uint64_t)__float_as_uint(p) << 32) | (uint64_t)idx;
}

// ---------------- IoU (bitwise-matched to reference) ----------------
__device__ __forceinline__ float iou_one(float4 a, float4 b) {
  #pragma clang fp contract(off)
  float tlx = fmaxf(a.x, b.x), tly = fmaxf(a.y, b.y);
  float brx = fminf(a.z, b.z), bry = fminf(a.w, b.w);
  float w = brx - tlx, h = bry - tly;
  float flag = (tlx < brx && tly < bry) ? 1.0f : 0.0f;
  float inter = w * h * flag;
  float area_a = (a.z - a.x) * (a.w - a.y);
  float area_b = (b.z - b.x) * (b.w - b.y);
  float u = (area_a + area_b) - inter;
  float r = inter / u;
  return fmaxf(r, 0.0f);
}

// variant with hoisted area_a (identical value: same expression, single rounding)
__device__ __forceinline__ float iou_area(float4 a, float4 b, float area_a) {
  #pragma clang fp contract(off)
  float tlx = fmaxf(a.x, b.x), tly = fmaxf(a.y, b.y);
  float brx = fminf(a.z, b.z), bry = fminf(a.w, b.w);
  float w = brx - tlx, h = bry - tly;
  float flag = (tlx < brx && tly < bry) ? 1.0f : 0.0f;
  float inter = w * h * flag;
  float area_b = (b.z - b.x) * (b.w - b.y);
  float u = (area_a + area_b) - inter;
  float r = inter / u;
  return fmaxf(r, 0.0f);
}

// DPP max step: template params so the builtin sees constant integers.
// bound_ctrl=false -> masked-out/invalid source lanes keep old (= x): identity-preserving.
template <int CTRL, int RMASK>
__device__ __forceinline__ uint32_t dpp_umax(uint32_t x) {
  uint32_t t = (uint32_t)__builtin_amdgcn_update_dpp((int)x, (int)x, CTRL, RMASK, 0xf, false);
  return x > t ? x : t;
}

struct ScalarBlk {
  unsigned long long cutoff[2];
  int B_pos, r_pos, B_neg, r_neg;
  int do_pos, do_neg, pos_kept, pad;
};

// K1 (fused): one IoU eval feeds BOTH per-anchor argmax (register) and
// per-gt argmax (DPP wave-reduce + LDS atomic). Block = 128 anchors x 256 gts,
// 256 threads: t&127 = local anchor, t>>7 = gt half. 1024 blocks -> 16 waves/CU.
__global__ __launch_bounds__(256) void k_fused(const float4* __restrict__ anchor,
                                               const float4* __restrict__ bbox,
                                               int* __restrict__ argmax,
                                               int* __restrict__ label,
                                               unsigned long long* __restrict__ gkey) {
  __shared__ float4 gts[G_BOX];
  __shared__ unsigned long long gkey_l[G_BOX];
  __shared__ uint32_t xbest[256];
  __shared__ int xbidx[256];
  int tid = threadIdx.x;
  int al = tid & 127, half = tid >> 7;
  int abase = blockIdx.x * 128;
  int i = abase + al;

  gts[tid] = bbox[tid];
  gkey_l[tid] = 0ull;
  __syncthreads();

  float4 a = anchor[i];
  float area_a;
  {
    #pragma clang fp contract(off)
    area_a = (a.z - a.x) * (a.w - a.y);
  }
  int wave_a0 = abase + ((tid >> 6) & 1) * 64;  // first anchor of this wave's 64
  uint32_t bestbits = 0u; int bidx = 0;         // iou>=0 -> u32 cmp == f32 cmp
  int gbase = half * 128;

  #pragma unroll 4
  for (int s = 0; s < 128; ++s) {
    int g = gbase + s;
    float4 b = gts[g];                          // broadcast ds_read_b128
    float v = iou_area(a, b, area_a);
    uint32_t vb = __float_as_uint(v);
    // per-anchor first-max (ascending g)
    if (vb > bestbits) { bestbits = vb; bidx = g; }
    // per-gt wave max via DPP (lane 63 ends with wave max)
    uint32_t x = vb;
    x = dpp_umax<0x111, 0xf>(x);  // row_shr:1
    x = dpp_umax<0x112, 0xf>(x);  // row_shr:2
    x = dpp_umax<0x114, 0xf>(x);  // row_shr:4
    x = dpp_umax<0x118, 0xf>(x);  // row_shr:8
    x = dpp_umax<0x142, 0xa>(x);  // row_bcast:15 -> rows 1,3
    x = dpp_umax<0x143, 0xc>(x);  // row_bcast:31 -> rows 2,3
    uint32_t m = (uint32_t)__builtin_amdgcn_readlane((int)x, 63);
    unsigned long long ball = __ballot(vb == m);
    int lane = __ffsll((long long)ball) - 1;    // lowest lane = smallest anchor idx
    unsigned long long key =
        ((unsigned long long)m << 32) |
        (unsigned long long)(~(uint32_t)(wave_a0 + lane));
    if ((tid & 63) == 0) atomicMax(&gkey_l[g], key);
  }

  __syncthreads();  // gkey_l complete; publish per-anchor halves
  xbest[tid] = bestbits; xbidx[tid] = bidx;
  __syncthreads();
  if (tid < 128) {
    uint32_t ob = xbest[tid + 128]; int og = xbidx[tid + 128];
    if (ob > bestbits) { bestbits = ob; bidx = og; }  // tie -> half0 (smaller g)
    argmax[i] = bidx;
    float best = __uint_as_float(bestbits);
    int lbl = -1;
    if (best < 0.3f) lbl = 0;
    if (best >= 0.7f) lbl = 1;
    label[i] = lbl;
  }
  atomicMax(&gkey[tid], gkey_l[tid]);  // order-independent, replay-safe
}

// K3: force gt-best anchors: label=1, argmax=g (sequential last-wins like scatter)
__global__ void k_force(const unsigned long long* __restrict__ gkey,
                        int* __restrict__ argmax, int* __restrict__ label) {
  __shared__ int ga[G_BOX];
  int tid = threadIdx.x;
  ga[tid] = (int)(~(uint32_t)(gkey[tid] & 0xffffffffull));
  __syncthreads();
  label[ga[tid]] = 1;
  if (tid == 0) {
    for (int t = 0; t < G_BOX; ++t) argmax[ga[t]] = t;
  }
}

// K4: histogram of priorities over 1024 buckets, per class
__global__ __launch_bounds__(256) void k_hist(const int* __restrict__ label,
                                              uint32_t* __restrict__ hist) {
  int i = blockIdx.x * 256 + threadIdx.x;
  int lbl = label[i];
  if (lbl < 0) return;
  TF2 k = (lbl == 1) ? KPOS : KNEG;
  float p = p_from_bits(rbits(k, (uint32_t)i));
  int b = (int)(p * 1024.0f); if (b > 1023) b = 1023;
  atomicAdd((unsigned int*)&hist[(lbl == 1 ? 0 : 1024) + b], 1u);
}

// K5: find boundary bucket + in-bucket rank for pos and neg
__global__ __launch_bounds__(256) void k_select(const uint32_t* __restrict__ hist,
                                                ScalarBlk* __restrict__ sc) {
  __shared__ uint32_t h[2048];
  for (int t = threadIdx.x; t < 2048; t += 256) h[t] = hist[t];
  __syncthreads();
  if (threadIdx.x != 0) return;
  uint32_t total_pos = 0, total_neg = 0;
  for (int b = 0; b < 1024; ++b) total_pos += h[b];
  for (int b = 0; b < 1024; ++b) total_neg += h[1024 + b];
  int pos_kept = total_pos < (uint32_t)NPOS_TGT ? (int)total_pos : NPOS_TGT;
  int n_neg = NSAMPLE - pos_kept;
  sc->pos_kept = pos_kept;
  if (total_pos <= (uint32_t)NPOS_TGT) {
    sc->do_pos = 0; sc->cutoff[0] = ~0ull;
  } else {
    uint32_t cum = 0; int B = 0;
    for (; B < 1024; ++B) { if (cum + h[B] > (uint32_t)NPOS_TGT) break; cum += h[B]; }
    sc->do_pos = 1; sc->B_pos = B; sc->r_pos = NPOS_TGT - (int)cum;
  }
  if (total_neg <= (uint32_t)n_neg) {
    sc->do_neg = 0; sc->cutoff[1] = ~0ull;
  } else {
    uint32_t cum = 0; int B = 0;
    for (; B < 1024; ++B) { if (cum + h[1024 + B] > (uint32_t)n_neg) break; cum += h[1024 + B]; }
    sc->do_neg = 1; sc->B_neg = B; sc->r_neg = n_neg - (int)cum;
  }
}

// K6: collect boundary-bucket members
__global__ __launch_bounds__(256) void k_collect(const int* __restrict__ label,
                                                 uint64_t* __restrict__ pos_list,
                                                 uint64_t* __restrict__ neg_list,
                                                 uint32_t* __restrict__ counters,
                                                 const ScalarBlk* __restrict__ sc) {
  int i = blockIdx.x * 256 + threadIdx.x;
  int lbl = label[i];
  if (lbl < 0) return;
  if (lbl == 1) {
    if (!sc->do_pos) return;
    float p = p_from_bits(rbits(KPOS, (uint32_t)i));
    int b = (int)(p * 1024.0f); if (b > 1023) b = 1023;
    if (b != sc->B_pos) return;
    uint32_t slot = atomicAdd((unsigned int*)&counters[0], 1u);
    if (slot < POS_CAP) pos_list[slot] = prio_key(p, (uint32_t)i);
  } else {
    if (!sc->do_neg) return;
    float p = p_from_bits(rbits(KNEG, (uint32_t)i));
    int b = (int)(p * 1024.0f); if (b > 1023) b = 1023;
    if (b != sc->B_neg) return;
    uint32_t slot = atomicAdd((unsigned int*)&counters[1], 1u);
    if (slot < NEG_CAP) neg_list[slot] = prio_key(p, (uint32_t)i);
  }
}

// K7: exact r-th smallest key within boundary bucket -> cutoff
__global__ __launch_bounds__(256) void k_cutoff(const uint64_t* __restrict__ pos_list,
                                                const uint64_t* __restrict__ neg_list,
                                                const uint32_t* __restrict__ counters,
                                                ScalarBlk* __restrict__ sc) {
  int cls = blockIdx.x;
  int doit = (cls == 0) ? sc->do_pos : sc->do_neg;
  if (!doit) return;
  const uint64_t* list = (cls == 0) ? pos_list : neg_list;
  int cap = (cls == 0) ? POS_CAP : NEG_CAP;
  int m = (int)counters[cls]; if (m > cap) m = cap;
  int r = (cls == 0) ? sc->r_pos : sc->r_neg;
  for (int j = threadIdx.x; j < m; j += 256) {
    uint64_t kj = list[j];
    int rank = 0;
    for (int t = 0; t < m; ++t) rank += (list[t] < kj) ? 1 : 0;
    if (rank == r) sc->cutoff[cls] = (unsigned long long)kj;
  }
}

// K8: final labels + bbox2loc
__global__ __launch_bounds__(256) void k_final(const float4* __restrict__ anchor,
                                               const float4* __restrict__ bbox,
                                               const int* __restrict__ argmax,
                                               const int* __restrict__ label,
                                               const ScalarBlk* __restrict__ sc,
                                               float* __restrict__ out) {
  #pragma clang fp contract(off)
  int i = blockIdx.x * 256 + threadIdx.x;
  int lbl = label[i];
  if (lbl == 1) {
    float p = p_from_bits(rbits(KPOS, (uint32_t)i));
    if (prio_key(p, (uint32_t)i) >= sc->cutoff[0]) lbl = -1;
  } else if (lbl == 0) {
    float p = p_from_bits(rbits(KNEG, (uint32_t)i));
    if (prio_key(p, (uint32_t)i) >= sc->cutoff[1]) lbl = -1;
  }
  out[K_ANCH * 4 + i] = (float)lbl;

  float4 a = anchor[i];
  float4 b = bbox[argmax[i]];
  const float eps = 1.1920928955078125e-07f;
  float w  = fmaxf(a.z - a.x, eps);
  float h  = fmaxf(a.w - a.y, eps);
  float cx = a.x + 0.5f * (a.z - a.x);
  float cy = a.y + 0.5f * (a.w - a.y);
  float bw = b.z - b.x, bh = b.w - b.y;
  float bcx = b.x + 0.5f * bw, bcy = b.y + 0.5f * bh;
  float dx = (bcx - cx) / w, dy = (bcy - cy) / h;
  float dw = logf(bw / w), dh = logf(bh / h);
  float4 o;
  if (sc->pos_kept > 0) o = make_float4(dx, dy, dw, dh);
  else o = make_float4(0.f, 0.f, 0.f, 0.f);
  ((float4*)out)[i] = o;
}

extern "C" void kernel_launch(void* const* d_in, const int* in_sizes, int n_in,
                              void* d_out, int out_size, void* d_ws, size_t ws_size,
                              hipStream_t stream) {
  const float4* anchor = (const float4*)d_in[0];
  const float4* bbox   = (const float4*)d_in[1];
  char* ws = (char*)d_ws;

  uint32_t* hist     = (uint32_t*)(ws);                   // [0, 8192)
  uint32_t* counters = (uint32_t*)(ws + 8192);            // [8192, 8200)
  unsigned long long* gkey = (unsigned long long*)(ws + 8704);  // [8704, 10752)
  ScalarBlk* sc      = (ScalarBlk*)(ws + 10752);
  int* argmax        = (int*)(ws + 16384);                // 512 KB
  int* label         = (int*)(ws + 16384 + 524288);       // 512 KB
  uint64_t* pos_list = (uint64_t*)(ws + 16384 + 1048576);
  uint64_t* neg_list = pos_list + POS_CAP;

  (void)hipMemsetAsync(ws, 0, 10752, stream);  // hist + counters + gkey
  k_fused  <<<1024, 256, 0, stream>>>(anchor, bbox, argmax, label, gkey);
  k_force  <<<1,    256, 0, stream>>>(gkey, argmax, label);
  k_hist   <<<512,  256, 0, stream>>>(label, hist);
  k_select <<<1,    256, 0, stream>>>(hist, sc);
  k_collect<<<512,  256, 0, stream>>>(label, pos_list, neg_list, counters, sc);
  k_cutoff <<<2,    256, 0, stream>>>(pos_list, neg_list, counters, sc);
  k_final  <<<512,  256, 0, stream>>>(anchor, bbox, argmax, label, sc, (float*)d_out);
}

// Round 9
// 143.000 us; speedup vs baseline: 2.0498x; 1.0626x over previous
//
#include <hip/hip_runtime.h>
#include <stdint.h>

#define K_ANCH 131072
#define G_BOX  256
#define NPOS_TGT 128
#define NSAMPLE 256
#define POS_CAP 8192
#define NEG_CAP 32768

// ---------------- Threefry-2x32-20 (JAX-compatible) ----------------
struct TF2 { uint32_t a, b; };

__host__ __device__ constexpr uint32_t rotl32(uint32_t v, int d) {
  return (v << d) | (v >> (32 - d));
}

__host__ __device__ constexpr TF2 threefry(uint32_t k0, uint32_t k1,
                                           uint32_t x0, uint32_t x1) {
  const uint32_t ks0 = k0, ks1 = k1, ks2 = k0 ^ k1 ^ 0x1BD11BDAu;
  const int R0[4] = {13, 15, 26, 6};
  const int R1[4] = {17, 29, 16, 24};
  x0 += ks0; x1 += ks1;
  for (int r = 0; r < 4; ++r) { x0 += x1; x1 = rotl32(x1, R0[r]); x1 ^= x0; }
  x0 += ks1; x1 += ks2 + 1u;
  for (int r = 0; r < 4; ++r) { x0 += x1; x1 = rotl32(x1, R1[r]); x1 ^= x0; }
  x0 += ks2; x1 += ks0 + 2u;
  for (int r = 0; r < 4; ++r) { x0 += x1; x1 = rotl32(x1, R0[r]); x1 ^= x0; }
  x0 += ks0; x1 += ks1 + 3u;
  for (int r = 0; r < 4; ++r) { x0 += x1; x1 = rotl32(x1, R1[r]); x1 ^= x0; }
  x0 += ks1; x1 += ks2 + 4u;
  for (int r = 0; r < 4; ++r) { x0 += x1; x1 = rotl32(x1, R0[r]); x1 ^= x0; }
  x0 += ks2; x1 += ks0 + 5u;
  return TF2{x0, x1};
}

constexpr TF2 KPOS = threefry(0u, 42u, 0u, 0u);  // k1 -> p_pos
constexpr TF2 KNEG = threefry(0u, 42u, 0u, 1u);  // k2 -> p_neg

__device__ __forceinline__ uint32_t rbits(TF2 k, uint32_t i) {
  TF2 r = threefry(k.a, k.b, 0u, i);
  return r.a ^ r.b;
}

__device__ __forceinline__ float p_from_bits(uint32_t bits) {
  uint32_t fb = 0x3f800000u | (bits >> 9);
  float f = __uint_as_float(fb) - 1.0f;
  return fmaxf(f, 0.0f);
}

__device__ __forceinline__ uint64_t prio_key(float p, uint32_t idx) {
  return ((uint64_t)__float_as_uint(p) << 32) | (uint64_t)idx;
}

// DPP max step: template params so the builtin sees constant integers.
// bound_ctrl=false -> invalid source lanes keep old (= x): identity-preserving.
template <int CTRL, int RMASK>
__device__ __forceinline__ uint32_t dpp_umax(uint32_t x) {
  uint32_t t = (uint32_t)__builtin_amdgcn_update_dpp((int)x, (int)x, CTRL, RMASK, 0xf, false);
  return x > t ? x : t;
}

struct ScalarBlk {
  unsigned long long cutoff[2];
  int B_pos, r_pos, B_neg, r_neg;
  int do_pos, do_neg, pos_kept, pad;
};

// K1 (fused): one IoU eval feeds BOTH per-anchor argmax (register) and per-gt
// argmax (DPP wave-reduce -> lane-select accumulation -> 1 global atomic/thread).
// Block = 64 anchors x 256 gts; 256 threads: lane=tid&63 -> anchor,
// wave q=tid>>6 -> gt range [64q,64q+64). 2048 blocks -> 32 waves/CU.
__global__ __launch_bounds__(256) void k_fused(const float4* __restrict__ anchor,
                                               const float4* __restrict__ bbox,
                                               int* __restrict__ argmax,
                                               int* __restrict__ label,
                                               unsigned long long* __restrict__ gkey_part) {
  __shared__ float4 gts[G_BOX];
  __shared__ float gab[G_BOX];          // precomputed area_b (bitwise-same product)
  __shared__ uint32_t xbest[256];
  __shared__ int xbidx[256];
  int tid = threadIdx.x;
  int al = tid & 63, q = tid >> 6;
  int abase = blockIdx.x * 64;
  int i = abase + al;

  float4 bb = bbox[tid];
  gts[tid] = bb;
  {
    #pragma clang fp contract(off)
    gab[tid] = (bb.z - bb.x) * (bb.w - bb.y);
  }
  __syncthreads();

  float4 a = anchor[i];
  float area_a;
  {
    #pragma clang fp contract(off)
    area_a = (a.z - a.x) * (a.w - a.y);
  }
  uint32_t bestbits = 0u; int bidx = 0;   // iou >= +0 -> u32 cmp == f32 cmp
  int gbase = q * 64;
  uint32_t keyhi = 0u, keylo = 0u;        // lane s accumulates gt (gbase+s) key

  #pragma unroll 8
  for (int s = 0; s < 64; ++s) {
    int g = gbase + s;
    float4 b = gts[g];                    // broadcast ds_read_b128
    float ab = gab[g];                    // broadcast ds_read_b32
    uint32_t vb;
    {
      #pragma clang fp contract(off)
      float tlx = fmaxf(a.x, b.x), tly = fmaxf(a.y, b.y);
      float brx = fminf(a.z, b.z), bry = fminf(a.w, b.w);
      float w = brx - tlx, h = bry - tly;
      float wh = w * h;
      bool ok = (tlx < brx) && (tly < bry);
      float inter = ok ? wh : 0.0f;       // == wh*flag; +0 always (no -0 path)
      float u = (area_a + ab) - inter;
      float v = inter / u;                // IEEE div, v >= +0
      vb = __float_as_uint(v);
    }
    // per-anchor first-max (ascending g)
    if (vb > bestbits) { bestbits = vb; bidx = g; }
    // per-gt wave max via DPP tree; lane 63 ends with wave max
    uint32_t x = vb;
    x = dpp_umax<0x111, 0xf>(x);  // row_shr:1
    x = dpp_umax<0x112, 0xf>(x);  // row_shr:2
    x = dpp_umax<0x114, 0xf>(x);  // row_shr:4
    x = dpp_umax<0x118, 0xf>(x);  // row_shr:8
    x = dpp_umax<0x142, 0xa>(x);  // row_bcast:15 -> rows 1,3
    x = dpp_umax<0x143, 0xc>(x);  // row_bcast:31 -> rows 2,3
    uint32_t m = (uint32_t)__builtin_amdgcn_readlane((int)x, 63);  // SGPR
    unsigned long long ball = __ballot(vb == m);
    int lane = __ffsll((long long)ball) - 1;        // lowest lane = smallest anchor
    uint32_t klo = ~(uint32_t)(abase + lane);       // SGPR
    // deposit wave-uniform (m, klo) into lane s: v_cmp + 2x v_cndmask
    bool mine = (al == s);
    keyhi = mine ? m : keyhi;
    keylo = mine ? klo : keylo;
  }

  // publish per-gt keys: lane al holds gt (gbase+al); 8-way partition cuts
  // per-address contention 2048 -> 256. Order-independent, replay-safe.
  {
    unsigned long long key = ((unsigned long long)keyhi << 32) | (unsigned long long)keylo;
    atomicMax(&gkey_part[(blockIdx.x & 7) * G_BOX + gbase + al], key);
  }

  // per-anchor merge across the 4 gt-quarters (ascending q -> first-max ties)
  xbest[tid] = bestbits; xbidx[tid] = bidx;
  __syncthreads();
  if (tid < 64) {
    #pragma unroll
    for (int qq = 1; qq < 4; ++qq) {
      uint32_t ob = xbest[qq * 64 + tid]; int og = xbidx[qq * 64 + tid];
      if (ob > bestbits) { bestbits = ob; bidx = og; }
    }
    argmax[i] = bidx;
    float best = __uint_as_float(bestbits);
    int lbl = -1;
    if (best < 0.3f) lbl = 0;
    if (best >= 0.7f) lbl = 1;
    label[i] = lbl;
  }
}

// K3: reduce 8 gkey partitions; force gt-best anchors (last-wins scatter)
__global__ void k_force(const unsigned long long* __restrict__ gkey_part,
                        int* __restrict__ argmax, int* __restrict__ label) {
  __shared__ int ga[G_BOX];
  int tid = threadIdx.x;
  unsigned long long best = gkey_part[tid];
  #pragma unroll
  for (int p = 1; p < 8; ++p) {
    unsigned long long o = gkey_part[p * G_BOX + tid];
    if (o > best) best = o;
  }
  ga[tid] = (int)(~(uint32_t)(best & 0xffffffffull));
  __syncthreads();
  label[ga[tid]] = 1;
  if (tid == 0) {
    for (int t = 0; t < G_BOX; ++t) argmax[ga[t]] = t;
  }
}

// K4: histogram of priorities over 1024 buckets, per class
__global__ __launch_bounds__(256) void k_hist(const int* __restrict__ label,
                                              uint32_t* __restrict__ hist) {
  int i = blockIdx.x * 256 + threadIdx.x;
  int lbl = label[i];
  if (lbl < 0) return;
  TF2 k = (lbl == 1) ? KPOS : KNEG;
  float p = p_from_bits(rbits(k, (uint32_t)i));
  int b = (int)(p * 1024.0f); if (b > 1023) b = 1023;
  atomicAdd((unsigned int*)&hist[(lbl == 1 ? 0 : 1024) + b], 1u);
}

// K5: find boundary bucket + in-bucket rank for pos and neg
__global__ __launch_bounds__(256) void k_select(const uint32_t* __restrict__ hist,
                                                ScalarBlk* __restrict__ sc) {
  __shared__ uint32_t h[2048];
  for (int t = threadIdx.x; t < 2048; t += 256) h[t] = hist[t];
  __syncthreads();
  if (threadIdx.x != 0) return;
  uint32_t total_pos = 0, total_neg = 0;
  for (int b = 0; b < 1024; ++b) total_pos += h[b];
  for (int b = 0; b < 1024; ++b) total_neg += h[1024 + b];
  int pos_kept = total_pos < (uint32_t)NPOS_TGT ? (int)total_pos : NPOS_TGT;
  int n_neg = NSAMPLE - pos_kept;
  sc->pos_kept = pos_kept;
  if (total_pos <= (uint32_t)NPOS_TGT) {
    sc->do_pos = 0; sc->cutoff[0] = ~0ull;
  } else {
    uint32_t cum = 0; int B = 0;
    for (; B < 1024; ++B) { if (cum + h[B] > (uint32_t)NPOS_TGT) break; cum += h[B]; }
    sc->do_pos = 1; sc->B_pos = B; sc->r_pos = NPOS_TGT - (int)cum;
  }
  if (total_neg <= (uint32_t)n_neg) {
    sc->do_neg = 0; sc->cutoff[1] = ~0ull;
  } else {
    uint32_t cum = 0; int B = 0;
    for (; B < 1024; ++B) { if (cum + h[1024 + B] > (uint32_t)n_neg) break; cum += h[1024 + B]; }
    sc->do_neg = 1; sc->B_neg = B; sc->r_neg = n_neg - (int)cum;
  }
}

// K6: collect boundary-bucket members
__global__ __launch_bounds__(256) void k_collect(const int* __restrict__ label,
                                                 uint64_t* __restrict__ pos_list,
                                                 uint64_t* __restrict__ neg_list,
                                                 uint32_t* __restrict__ counters,
                                                 const ScalarBlk* __restrict__ sc) {
  int i = blockIdx.x * 256 + threadIdx.x;
  int lbl = label[i];
  if (lbl < 0) return;
  if (lbl == 1) {
    if (!sc->do_pos) return;
    float p = p_from_bits(rbits(KPOS, (uint32_t)i));
    int b = (int)(p * 1024.0f); if (b > 1023) b = 1023;
    if (b != sc->B_pos) return;
    uint32_t slot = atomicAdd((unsigned int*)&counters[0], 1u);
    if (slot < POS_CAP) pos_list[slot] = prio_key(p, (uint32_t)i);
  } else {
    if (!sc->do_neg) return;
    float p = p_from_bits(rbits(KNEG, (uint32_t)i));
    int b = (int)(p * 1024.0f); if (b > 1023) b = 1023;
    if (b != sc->B_neg) return;
    uint32_t slot = atomicAdd((unsigned int*)&counters[1], 1u);
    if (slot < NEG_CAP) neg_list[slot] = prio_key(p, (uint32_t)i);
  }
}

// K7: exact r-th smallest key within boundary bucket -> cutoff
__global__ __launch_bounds__(256) void k_cutoff(const uint64_t* __restrict__ pos_list,
                                                const uint64_t* __restrict__ neg_list,
                                                const uint32_t* __restrict__ counters,
                                                ScalarBlk* __restrict__ sc) {
  int cls = blockIdx.x;
  int doit = (cls == 0) ? sc->do_pos : sc->do_neg;
  if (!doit) return;
  const uint64_t* list = (cls == 0) ? pos_list : neg_list;
  int cap = (cls == 0) ? POS_CAP : NEG_CAP;
  int m = (int)counters[cls]; if (m > cap) m = cap;
  int r = (cls == 0) ? sc->r_pos : sc->r_neg;
  for (int j = threadIdx.x; j < m; j += 256) {
    uint64_t kj = list[j];
    int rank = 0;
    for (int t = 0; t < m; ++t) rank += (list[t] < kj) ? 1 : 0;
    if (rank == r) sc->cutoff[cls] = (unsigned long long)kj;
  }
}

// K8: final labels + bbox2loc
__global__ __launch_bounds__(256) void k_final(const float4* __restrict__ anchor,
                                               const float4* __restrict__ bbox,
                                               const int* __restrict__ argmax,
                                               const int* __restrict__ label,
                                               const ScalarBlk* __restrict__ sc,
                                               float* __restrict__ out) {
  #pragma clang fp contract(off)
  int i = blockIdx.x * 256 + threadIdx.x;
  int lbl = label[i];
  if (lbl == 1) {
    float p = p_from_bits(rbits(KPOS, (uint32_t)i));
    if (prio_key(p, (uint32_t)i) >= sc->cutoff[0]) lbl = -1;
  } else if (lbl == 0) {
    float p = p_from_bits(rbits(KNEG, (uint32_t)i));
    if (prio_key(p, (uint32_t)i) >= sc->cutoff[1]) lbl = -1;
  }
  out[K_ANCH * 4 + i] = (float)lbl;

  float4 a = anchor[i];
  float4 b = bbox[argmax[i]];
  const float eps = 1.1920928955078125e-07f;
  float w  = fmaxf(a.z - a.x, eps);
  float h  = fmaxf(a.w - a.y, eps);
  float cx = a.x + 0.5f * (a.z - a.x);
  float cy = a.y + 0.5f * (a.w - a.y);
  float bw = b.z - b.x, bh = b.w - b.y;
  float bcx = b.x + 0.5f * bw, bcy = b.y + 0.5f * bh;
  float dx = (bcx - cx) / w, dy = (bcy - cy) / h;
  float dw = logf(bw / w), dh = logf(bh / h);
  float4 o;
  if (sc->pos_kept > 0) o = make_float4(dx, dy, dw, dh);
  else o = make_float4(0.f, 0.f, 0.f, 0.f);
  ((float4*)out)[i] = o;
}

extern "C" void kernel_launch(void* const* d_in, const int* in_sizes, int n_in,
                              void* d_out, int out_size, void* d_ws, size_t ws_size,
                              hipStream_t stream) {
  const float4* anchor = (const float4*)d_in[0];
  const float4* bbox   = (const float4*)d_in[1];
  char* ws = (char*)d_ws;

  uint32_t* hist     = (uint32_t*)(ws);                   // [0, 8192)
  uint32_t* counters = (uint32_t*)(ws + 8192);            // [8192, 8200)
  unsigned long long* gkey_part = (unsigned long long*)(ws + 16384);  // 16 KB: [16384, 32768)
  ScalarBlk* sc      = (ScalarBlk*)(ws + 32768);
  int* argmax        = (int*)(ws + 65536);                // 512 KB
  int* label         = (int*)(ws + 65536 + 524288);       // 512 KB
  uint64_t* pos_list = (uint64_t*)(ws + 65536 + 1048576);
  uint64_t* neg_list = pos_list + POS_CAP;

  (void)hipMemsetAsync(ws, 0, 32768, stream);  // hist + counters + gkey_part
  k_fused  <<<2048, 256, 0, stream>>>(anchor, bbox, argmax, label, gkey_part);
  k_force  <<<1,    256, 0, stream>>>(gkey_part, argmax, label);
  k_hist   <<<512,  256, 0, stream>>>(label, hist);
  k_select <<<1,    256, 0, stream>>>(hist, sc);
  k_collect<<<512,  256, 0, stream>>>(label, pos_list, neg_list, counters, sc);
  k_cutoff <<<2,    256, 0, stream>>>(pos_list, neg_list, counters, sc);
  k_final  <<<512,  256, 0, stream>>>(anchor, bbox, argmax, label, sc, (float*)d_out);
}

// Round 10
// 136.614 us; speedup vs baseline: 2.1456x; 1.0467x over previous
//
#include <hip/hip_runtime.h>
#include <stdint.h>

#define K_ANCH 131072
#define G_BOX  256
#define NPOS_TGT 128
#define NSAMPLE 256
#define POS_CAP 8192
#define NEG_CAP 32768

// ---------------- Threefry-2x32-20 (JAX-compatible) ----------------
struct TF2 { uint32_t a, b; };

__host__ __device__ constexpr uint32_t rotl32(uint32_t v, int d) {
  return (v << d) | (v >> (32 - d));
}

__host__ __device__ constexpr TF2 threefry(uint32_t k0, uint32_t k1,
                                           uint32_t x0, uint32_t x1) {
  const uint32_t ks0 = k0, ks1 = k1, ks2 = k0 ^ k1 ^ 0x1BD11BDAu;
  const int R0[4] = {13, 15, 26, 6};
  const int R1[4] = {17, 29, 16, 24};
  x0 += ks0; x1 += ks1;
  for (int r = 0; r < 4; ++r) { x0 += x1; x1 = rotl32(x1, R0[r]); x1 ^= x0; }
  x0 += ks1; x1 += ks2 + 1u;
  for (int r = 0; r < 4; ++r) { x0 += x1; x1 = rotl32(x1, R1[r]); x1 ^= x0; }
  x0 += ks2; x1 += ks0 + 2u;
  for (int r = 0; r < 4; ++r) { x0 += x1; x1 = rotl32(x1, R0[r]); x1 ^= x0; }
  x0 += ks0; x1 += ks1 + 3u;
  for (int r = 0; r < 4; ++r) { x0 += x1; x1 = rotl32(x1, R1[r]); x1 ^= x0; }
  x0 += ks1; x1 += ks2 + 4u;
  for (int r = 0; r < 4; ++r) { x0 += x1; x1 = rotl32(x1, R0[r]); x1 ^= x0; }
  x0 += ks2; x1 += ks0 + 5u;
  return TF2{x0, x1};
}

constexpr TF2 KPOS = threefry(0u, 42u, 0u, 0u);  // k1 -> p_pos
constexpr TF2 KNEG = threefry(0u, 42u, 0u, 1u);  // k2 -> p_neg

__device__ __forceinline__ uint32_t rbits(TF2 k, uint32_t i) {
  TF2 r = threefry(k.a, k.b, 0u, i);
  return r.a ^ r.b;
}

__device__ __forceinline__ float p_from_bits(uint32_t bits) {
  uint32_t fb = 0x3f800000u | (bits >> 9);
  float f = __uint_as_float(fb) - 1.0f;
  return fmaxf(f, 0.0f);
}

__device__ __forceinline__ uint64_t prio_key(float p, uint32_t idx) {
  return ((uint64_t)__float_as_uint(p) << 32) | (uint64_t)idx;
}

// DPP max step: template params so the builtin sees constant integers.
// bound_ctrl=false -> invalid source lanes keep old (= x): identity-preserving.
template <int CTRL, int RMASK>
__device__ __forceinline__ uint32_t dpp_umax(uint32_t x) {
  uint32_t t = (uint32_t)__builtin_amdgcn_update_dpp((int)x, (int)x, CTRL, RMASK, 0xf, false);
  return x > t ? x : t;
}

// IoU bitwise-matched to reference (contract off, select-form inter -> always +0)
__device__ __forceinline__ uint32_t iou_bits(float4 a, float area_a, float4 b, float ab) {
  #pragma clang fp contract(off)
  float tlx = fmaxf(a.x, b.x), tly = fmaxf(a.y, b.y);
  float brx = fminf(a.z, b.z), bry = fminf(a.w, b.w);
  float w = brx - tlx, h = bry - tly;
  float wh = w * h;
  bool ok = (tlx < brx) && (tly < bry);
  float inter = ok ? wh : 0.0f;
  float u = (area_a + ab) - inter;
  float v = inter / u;                // IEEE div, v >= +0
  return __float_as_uint(v);
}

struct ScalarBlk {
  unsigned long long cutoff[2];
  int B_pos, r_pos, B_neg, r_neg;
  int do_pos, do_neg, pos_kept, pad;
};

// K1 (fused, 2 anchors/lane): one IoU pass feeds per-anchor argmax (registers)
// and per-gt argmax (ONE DPP tree per gt per 128 anchors -> amortized).
// Block = 128 anchors x 256 gts; wave q owns gt quarter [64q,64q+64);
// lane al holds anchors abase+al and abase+64+al. 1024 blocks -> 16 waves/CU.
__global__ __launch_bounds__(256) void k_fused(const float4* __restrict__ anchor,
                                               const float4* __restrict__ bbox,
                                               int* __restrict__ argmax,
                                               int* __restrict__ label,
                                               unsigned long long* __restrict__ gkey_part) {
  __shared__ float4 gts[G_BOX];
  __shared__ float gab[G_BOX];          // precomputed area_b (bitwise-same product)
  __shared__ uint32_t xb0[G_BOX], xb1[G_BOX];
  __shared__ int xi0[G_BOX], xi1[G_BOX];
  int tid = threadIdx.x;
  int al = tid & 63, q = tid >> 6;
  int abase = blockIdx.x * 128;
  int i0 = abase + al, i1 = abase + 64 + al;

  float4 bb = bbox[tid];
  gts[tid] = bb;
  {
    #pragma clang fp contract(off)
    gab[tid] = (bb.z - bb.x) * (bb.w - bb.y);
  }
  __syncthreads();

  float4 a0 = anchor[i0];
  float4 a1 = anchor[i1];
  float area0, area1;
  {
    #pragma clang fp contract(off)
    area0 = (a0.z - a0.x) * (a0.w - a0.y);
    area1 = (a1.z - a1.x) * (a1.w - a1.y);
  }
  uint32_t bb0 = 0u, bb1 = 0u; int bi0 = 0, bi1 = 0;  // iou>=+0 -> u32 cmp == f32 cmp
  int gbase = q * 64;
  uint32_t keyhi = 0u, keylo = 0u;        // lane s accumulates gt (gbase+s) key

  #pragma unroll 8
  for (int s = 0; s < 64; ++s) {
    int g = gbase + s;
    float4 b = gts[g];                    // broadcast ds_read_b128 (shared by both anchors)
    float ab = gab[g];                    // broadcast ds_read_b32
    uint32_t vb0 = iou_bits(a0, area0, b, ab);
    uint32_t vb1 = iou_bits(a1, area1, b, ab);
    // per-anchor first-max (ascending g)
    if (vb0 > bb0) { bb0 = vb0; bi0 = g; }
    if (vb1 > bb1) { bb1 = vb1; bi1 = g; }
    // local combine for per-gt max (tie -> anchor set 0 = smaller index)
    uint32_t cv = (vb1 > vb0) ? vb1 : vb0;
    // per-gt wave max via DPP tree; lane 63 ends with wave max
    uint32_t x = cv;
    x = dpp_umax<0x111, 0xf>(x);  // row_shr:1
    x = dpp_umax<0x112, 0xf>(x);  // row_shr:2
    x = dpp_umax<0x114, 0xf>(x);  // row_shr:4
    x = dpp_umax<0x118, 0xf>(x);  // row_shr:8
    x = dpp_umax<0x142, 0xa>(x);  // row_bcast:15 -> rows 1,3
    x = dpp_umax<0x143, 0xc>(x);  // row_bcast:31 -> rows 2,3
    uint32_t m = (uint32_t)__builtin_amdgcn_readlane((int)x, 63);  // SGPR
    // smallest global anchor with iou==m: all set-0 anchors < all set-1 anchors
    unsigned long long ball0 = __ballot(vb0 == m);
    unsigned long long ball1 = __ballot(vb1 == m);
    int idx = ball0 ? (abase + (__ffsll((long long)ball0) - 1))
                    : (abase + 64 + (__ffsll((long long)ball1) - 1));
    uint32_t klo = ~(uint32_t)idx;                  // SGPR, wave-uniform
    // deposit wave-uniform (m, klo) into lane s: v_cmp + 2x v_cndmask
    bool mine = (al == s);
    keyhi = mine ? m : keyhi;
    keylo = mine ? klo : keylo;
  }

  // publish per-gt keys: lane al holds gt (gbase+al); 8-way partition cuts
  // per-address contention. Order-independent, replay-safe.
  {
    unsigned long long key = ((unsigned long long)keyhi << 32) | (unsigned long long)keylo;
    atomicMax(&gkey_part[(blockIdx.x & 7) * G_BOX + gbase + al], key);
  }

  // per-anchor merge across the 4 gt-quarters (ascending q -> first-max ties)
  xb0[q * 64 + al] = bb0; xi0[q * 64 + al] = bi0;
  xb1[q * 64 + al] = bb1; xi1[q * 64 + al] = bi1;
  __syncthreads();
  if (tid < 128) {
    int al2 = tid & 63;
    const uint32_t* xb = (tid < 64) ? xb0 : xb1;   // wave-uniform select
    const int*      xi = (tid < 64) ? xi0 : xi1;
    uint32_t bestb = xb[al2]; int bidx = xi[al2];
    #pragma unroll
    for (int qq = 1; qq < 4; ++qq) {
      uint32_t ob = xb[qq * 64 + al2]; int og = xi[qq * 64 + al2];
      if (ob > bestb) { bestb = ob; bidx = og; }
    }
    int ia = abase + tid;                 // tid<64 -> set0 anchor; else set1
    argmax[ia] = bidx;
    float best = __uint_as_float(bestb);
    int lbl = -1;
    if (best < 0.3f) lbl = 0;
    if (best >= 0.7f) lbl = 1;
    label[ia] = lbl;
  }
}

// K3: reduce 8 gkey partitions; force gt-best anchors (last-wins scatter)
__global__ void k_force(const unsigned long long* __restrict__ gkey_part,
                        int* __restrict__ argmax, int* __restrict__ label) {
  __shared__ int ga[G_BOX];
  int tid = threadIdx.x;
  unsigned long long best = gkey_part[tid];
  #pragma unroll
  for (int p = 1; p < 8; ++p) {
    unsigned long long o = gkey_part[p * G_BOX + tid];
    if (o > best) best = o;
  }
  ga[tid] = (int)(~(uint32_t)(best & 0xffffffffull));
  __syncthreads();
  label[ga[tid]] = 1;
  if (tid == 0) {
    for (int t = 0; t < G_BOX; ++t) argmax[ga[t]] = t;
  }
}

// K4: histogram of priorities over 1024 buckets, per class
__global__ __launch_bounds__(256) void k_hist(const int* __restrict__ label,
                                              uint32_t* __restrict__ hist) {
  int i = blockIdx.x * 256 + threadIdx.x;
  int lbl = label[i];
  if (lbl < 0) return;
  TF2 k = (lbl == 1) ? KPOS : KNEG;
  float p = p_from_bits(rbits(k, (uint32_t)i));
  int b = (int)(p * 1024.0f); if (b > 1023) b = 1023;
  atomicAdd((unsigned int*)&hist[(lbl == 1 ? 0 : 1024) + b], 1u);
}

// K5: find boundary bucket + in-bucket rank for pos and neg
__global__ __launch_bounds__(256) void k_select(const uint32_t* __restrict__ hist,
                                                ScalarBlk* __restrict__ sc) {
  __shared__ uint32_t h[2048];
  for (int t = threadIdx.x; t < 2048; t += 256) h[t] = hist[t];
  __syncthreads();
  if (threadIdx.x != 0) return;
  uint32_t total_pos = 0, total_neg = 0;
  for (int b = 0; b < 1024; ++b) total_pos += h[b];
  for (int b = 0; b < 1024; ++b) total_neg += h[1024 + b];
  int pos_kept = total_pos < (uint32_t)NPOS_TGT ? (int)total_pos : NPOS_TGT;
  int n_neg = NSAMPLE - pos_kept;
  sc->pos_kept = pos_kept;
  if (total_pos <= (uint32_t)NPOS_TGT) {
    sc->do_pos = 0; sc->cutoff[0] = ~0ull;
  } else {
    uint32_t cum = 0; int B = 0;
    for (; B < 1024; ++B) { if (cum + h[B] > (uint32_t)NPOS_TGT) break; cum += h[B]; }
    sc->do_pos = 1; sc->B_pos = B; sc->r_pos = NPOS_TGT - (int)cum;
  }
  if (total_neg <= (uint32_t)n_neg) {
    sc->do_neg = 0; sc->cutoff[1] = ~0ull;
  } else {
    uint32_t cum = 0; int B = 0;
    for (; B < 1024; ++B) { if (cum + h[1024 + B] > (uint32_t)n_neg) break; cum += h[1024 + B]; }
    sc->do_neg = 1; sc->B_neg = B; sc->r_neg = n_neg - (int)cum;
  }
}

// K6: collect boundary-bucket members
__global__ __launch_bounds__(256) void k_collect(const int* __restrict__ label,
                                                 uint64_t* __restrict__ pos_list,
                                                 uint64_t* __restrict__ neg_list,
                                                 uint32_t* __restrict__ counters,
                                                 const ScalarBlk* __restrict__ sc) {
  int i = blockIdx.x * 256 + threadIdx.x;
  int lbl = label[i];
  if (lbl < 0) return;
  if (lbl == 1) {
    if (!sc->do_pos) return;
    float p = p_from_bits(rbits(KPOS, (uint32_t)i));
    int b = (int)(p * 1024.0f); if (b > 1023) b = 1023;
    if (b != sc->B_pos) return;
    uint32_t slot = atomicAdd((unsigned int*)&counters[0], 1u);
    if (slot < POS_CAP) pos_list[slot] = prio_key(p, (uint32_t)i);
  } else {
    if (!sc->do_neg) return;
    float p = p_from_bits(rbits(KNEG, (uint32_t)i));
    int b = (int)(p * 1024.0f); if (b > 1023) b = 1023;
    if (b != sc->B_neg) return;
    uint32_t slot = atomicAdd((unsigned int*)&counters[1], 1u);
    if (slot < NEG_CAP) neg_list[slot] = prio_key(p, (uint32_t)i);
  }
}

// K7: exact r-th smallest key within boundary bucket -> cutoff
__global__ __launch_bounds__(256) void k_cutoff(const uint64_t* __restrict__ pos_list,
                                                const uint64_t* __restrict__ neg_list,
                                                const uint32_t* __restrict__ counters,
                                                ScalarBlk* __restrict__ sc) {
  int cls = blockIdx.x;
  int doit = (cls == 0) ? sc->do_pos : sc->do_neg;
  if (!doit) return;
  const uint64_t* list = (cls == 0) ? pos_list : neg_list;
  int cap = (cls == 0) ? POS_CAP : NEG_CAP;
  int m = (int)counters[cls]; if (m > cap) m = cap;
  int r = (cls == 0) ? sc->r_pos : sc->r_neg;
  for (int j = threadIdx.x; j < m; j += 256) {
    uint64_t kj = list[j];
    int rank = 0;
    for (int t = 0; t < m; ++t) rank += (list[t] < kj) ? 1 : 0;
    if (rank == r) sc->cutoff[cls] = (unsigned long long)kj;
  }
}

// K8: final labels + bbox2loc
__global__ __launch_bounds__(256) void k_final(const float4* __restrict__ anchor,
                                               const float4* __restrict__ bbox,
                                               const int* __restrict__ argmax,
                                               const int* __restrict__ label,
                                               const ScalarBlk* __restrict__ sc,
                                               float* __restrict__ out) {
  #pragma clang fp contract(off)
  int i = blockIdx.x * 256 + threadIdx.x;
  int lbl = label[i];
  if (lbl == 1) {
    float p = p_from_bits(rbits(KPOS, (uint32_t)i));
    if (prio_key(p, (uint32_t)i) >= sc->cutoff[0]) lbl = -1;
  } else if (lbl == 0) {
    float p = p_from_bits(rbits(KNEG, (uint32_t)i));
    if (prio_key(p, (uint32_t)i) >= sc->cutoff[1]) lbl = -1;
  }
  out[K_ANCH * 4 + i] = (float)lbl;

  float4 a = anchor[i];
  float4 b = bbox[argmax[i]];
  const float eps = 1.1920928955078125e-07f;
  float w  = fmaxf(a.z - a.x, eps);
  float h  = fmaxf(a.w - a.y, eps);
  float cx = a.x + 0.5f * (a.z - a.x);
  float cy = a.y + 0.5f * (a.w - a.y);
  float bw = b.z - b.x, bh = b.w - b.y;
  float bcx = b.x + 0.5f * bw, bcy = b.y + 0.5f * bh;
  float dx = (bcx - cx) / w, dy = (bcy - cy) / h;
  float dw = logf(bw / w), dh = logf(bh / h);
  float4 o;
  if (sc->pos_kept > 0) o = make_float4(dx, dy, dw, dh);
  else o = make_float4(0.f, 0.f, 0.f, 0.f);
  ((float4*)out)[i] = o;
}

extern "C" void kernel_launch(void* const* d_in, const int* in_sizes, int n_in,
                              void* d_out, int out_size, void* d_ws, size_t ws_size,
                              hipStream_t stream) {
  const float4* anchor = (const float4*)d_in[0];
  const float4* bbox   = (const float4*)d_in[1];
  char* ws = (char*)d_ws;

  uint32_t* hist     = (uint32_t*)(ws);                   // [0, 8192)
  uint32_t* counters = (uint32_t*)(ws + 8192);            // [8192, 8200)
  unsigned long long* gkey_part = (unsigned long long*)(ws + 16384);  // 16 KB: [16384, 32768)
  ScalarBlk* sc      = (ScalarBlk*)(ws + 32768);
  int* argmax        = (int*)(ws + 65536);                // 512 KB
  int* label         = (int*)(ws + 65536 + 524288);       // 512 KB
  uint64_t* pos_list = (uint64_t*)(ws + 65536 + 1048576);
  uint64_t* neg_list = pos_list + POS_CAP;

  (void)hipMemsetAsync(ws, 0, 32768, stream);  // hist + counters + gkey_part
  k_fused  <<<1024, 256, 0, stream>>>(anchor, bbox, argmax, label, gkey_part);
  k_force  <<<1,    256, 0, stream>>>(gkey_part, argmax, label);
  k_hist   <<<512,  256, 0, stream>>>(label, hist);
  k_select <<<1,    256, 0, stream>>>(hist, sc);
  k_collect<<<512,  256, 0, stream>>>(label, pos_list, neg_list, counters, sc);
  k_cutoff <<<2,    256, 0, stream>>>(pos_list, neg_list, counters, sc);
  k_final  <<<512,  256, 0, stream>>>(anchor, bbox, argmax, label, sc, (float*)d_out);
}

// Round 11
// 129.700 us; speedup vs baseline: 2.2600x; 1.0533x over previous
//
#include <hip/hip_runtime.h>
#include <stdint.h>

#define K_ANCH 131072
#define G_BOX  256
#define NPOS_TGT 128
#define NSAMPLE 256
#define POS_CAP 8192
#define NEG_CAP 32768
#define NPART 16

// ---------------- Threefry-2x32-20 (JAX-compatible) ----------------
struct TF2 { uint32_t a, b; };

__host__ __device__ constexpr uint32_t rotl32(uint32_t v, int d) {
  return (v << d) | (v >> (32 - d));
}

__host__ __device__ constexpr TF2 threefry(uint32_t k0, uint32_t k1,
                                           uint32_t x0, uint32_t x1) {
  const uint32_t ks0 = k0, ks1 = k1, ks2 = k0 ^ k1 ^ 0x1BD11BDAu;
  const int R0[4] = {13, 15, 26, 6};
  const int R1[4] = {17, 29, 16, 24};
  x0 += ks0; x1 += ks1;
  for (int r = 0; r < 4; ++r) { x0 += x1; x1 = rotl32(x1, R0[r]); x1 ^= x0; }
  x0 += ks1; x1 += ks2 + 1u;
  for (int r = 0; r < 4; ++r) { x0 += x1; x1 = rotl32(x1, R1[r]); x1 ^= x0; }
  x0 += ks2; x1 += ks0 + 2u;
  for (int r = 0; r < 4; ++r) { x0 += x1; x1 = rotl32(x1, R0[r]); x1 ^= x0; }
  x0 += ks0; x1 += ks1 + 3u;
  for (int r = 0; r < 4; ++r) { x0 += x1; x1 = rotl32(x1, R1[r]); x1 ^= x0; }
  x0 += ks1; x1 += ks2 + 4u;
  for (int r = 0; r < 4; ++r) { x0 += x1; x1 = rotl32(x1, R0[r]); x1 ^= x0; }
  x0 += ks2; x1 += ks0 + 5u;
  return TF2{x0, x1};
}

constexpr TF2 KPOS = threefry(0u, 42u, 0u, 0u);  // k1 -> p_pos
constexpr TF2 KNEG = threefry(0u, 42u, 0u, 1u);  // k2 -> p_neg

__device__ __forceinline__ uint32_t rbits(TF2 k, uint32_t i) {
  TF2 r = threefry(k.a, k.b, 0u, i);
  return r.a ^ r.b;
}

__device__ __forceinline__ float p_from_bits(uint32_t bits) {
  uint32_t fb = 0x3f800000u | (bits >> 9);
  float f = __uint_as_float(fb) - 1.0f;
  return fmaxf(f, 0.0f);
}

__device__ __forceinline__ uint64_t prio_key(float p, uint32_t idx) {
  return ((uint64_t)__float_as_uint(p) << 32) | (uint64_t)idx;
}

// IoU bitwise-matched to reference (contract off, select-form inter -> always +0)
__device__ __forceinline__ uint32_t iou_bits(float4 a, float area_a, float4 b, float ab) {
  #pragma clang fp contract(off)
  float tlx = fmaxf(a.x, b.x), tly = fmaxf(a.y, b.y);
  float brx = fminf(a.z, b.z), bry = fminf(a.w, b.w);
  float w = brx - tlx, h = bry - tly;
  float wh = w * h;
  bool ok = (tlx < brx) && (tly < bry);
  float inter = ok ? wh : 0.0f;
  float u = (area_a + ab) - inter;
  float v = inter / u;                // IEEE div, v >= +0
  return __float_as_uint(v);
}

struct ScalarBlk {
  unsigned long long cutoff[2];
  int B_pos, r_pos, B_neg, r_neg;
  int do_pos, do_neg, pos_kept, pad;
};

// K1 (fused, LDS-tile): block = 64 anchors x 256 gts, 2048 blocks.
// Per 128-gt half: phase1 writes iou[c][al] to padded LDS tile while keeping
// per-anchor argmax in registers; phase2 (threads<128) column-scans one gt each
// -> per-gt argmax with ZERO cross-lane ops. No DPP/ballot/readlane.
__global__ __launch_bounds__(256) void k_fused(const float4* __restrict__ anchor,
                                               const float4* __restrict__ bbox,
                                               int* __restrict__ argmax,
                                               int* __restrict__ label,
                                               unsigned long long* __restrict__ gkey_part) {
  __shared__ float4 gts[G_BOX];
  __shared__ float gab[G_BOX];              // precomputed area_b (bitwise-same product)
  __shared__ uint32_t ioum[128 * 65];       // [c][a], pad 65 -> conflict-free both ways
  __shared__ uint32_t xb[4][64];
  __shared__ int xi[4][64];
  int tid = threadIdx.x;
  int al = tid & 63, q = tid >> 6;
  int abase = blockIdx.x * 64;
  int i = abase + al;

  float4 bbv = bbox[tid];
  gts[tid] = bbv;
  {
    #pragma clang fp contract(off)
    gab[tid] = (bbv.z - bbv.x) * (bbv.w - bbv.y);
  }
  __syncthreads();

  float4 a = anchor[i];
  float area_a;
  {
    #pragma clang fp contract(off)
    area_a = (a.z - a.x) * (a.w - a.y);
  }
  uint32_t bestbits = 0u; int bidx = 0;     // iou>=+0 -> u32 cmp == f32 cmp

  #pragma unroll
  for (int h = 0; h < 2; ++h) {
    int hg = h * 128;
    // phase1: thread (al,q) computes cols c = q*32+[0,32) of this half
    #pragma unroll 8
    for (int s = 0; s < 32; ++s) {
      int c = q * 32 + s;
      int g = hg + c;
      float4 b = gts[g];                    // broadcast ds_read_b128
      float ab = gab[g];
      uint32_t vb = iou_bits(a, area_a, b, ab);
      if (vb > bestbits) { bestbits = vb; bidx = g; }   // ascending g per thread
      ioum[c * 65 + al] = vb;               // lanes consecutive -> conflict-free
    }
    __syncthreads();                        // tile complete
    // phase2: threads 0..127 each scan one gt column (ascending a -> first-max)
    if (tid < 128) {
      int c = tid;
      uint32_t cb = ioum[c * 65 + 0]; int ca = 0;
      #pragma unroll 8
      for (int aa = 1; aa < 64; ++aa) {
        uint32_t v = ioum[c * 65 + aa];     // stride 65 across lanes -> conflict-free
        if (v > cb) { cb = v; ca = aa; }
      }
      unsigned long long key =
          ((unsigned long long)cb << 32) |
          (unsigned long long)(~(uint32_t)(abase + ca));
      atomicMax(&gkey_part[(blockIdx.x & (NPART - 1)) * G_BOX + hg + c], key);
    }
    __syncthreads();                        // column scans done before overwrite
  }

  // per-anchor merge across the 4 quarters (non-contiguous g-ranges -> explicit tie-break)
  xb[q][al] = bestbits; xi[q][al] = bidx;
  __syncthreads();
  if (tid < 64) {
    uint32_t bestb = xb[0][tid]; int bi = xi[0][tid];
    #pragma unroll
    for (int qq = 1; qq < 4; ++qq) {
      uint32_t ob = xb[qq][tid]; int og = xi[qq][tid];
      if (ob > bestb || (ob == bestb && og < bi)) { bestb = ob; bi = og; }
    }
    argmax[i] = bi;
    float best = __uint_as_float(bestb);
    int lbl = -1;
    if (best < 0.3f) lbl = 0;
    if (best >= 0.7f) lbl = 1;
    label[i] = lbl;
  }
}

// K3: reduce NPART gkey partitions; force gt-best anchors (last-wins scatter)
__global__ void k_force(const unsigned long long* __restrict__ gkey_part,
                        int* __restrict__ argmax, int* __restrict__ label) {
  __shared__ int ga[G_BOX];
  int tid = threadIdx.x;
  unsigned long long best = gkey_part[tid];
  #pragma unroll
  for (int p = 1; p < NPART; ++p) {
    unsigned long long o = gkey_part[p * G_BOX + tid];
    if (o > best) best = o;
  }
  ga[tid] = (int)(~(uint32_t)(best & 0xffffffffull));
  __syncthreads();
  label[ga[tid]] = 1;
  if (tid == 0) {
    for (int t = 0; t < G_BOX; ++t) argmax[ga[t]] = t;
  }
}

// K4: histogram of priorities over 1024 buckets, per class
__global__ __launch_bounds__(256) void k_hist(const int* __restrict__ label,
                                              uint32_t* __restrict__ hist) {
  int i = blockIdx.x * 256 + threadIdx.x;
  int lbl = label[i];
  if (lbl < 0) return;
  TF2 k = (lbl == 1) ? KPOS : KNEG;
  float p = p_from_bits(rbits(k, (uint32_t)i));
  int b = (int)(p * 1024.0f); if (b > 1023) b = 1023;
  atomicAdd((unsigned int*)&hist[(lbl == 1 ? 0 : 1024) + b], 1u);
}

// K5: find boundary bucket + in-bucket rank for pos and neg
__global__ __launch_bounds__(256) void k_select(const uint32_t* __restrict__ hist,
                                                ScalarBlk* __restrict__ sc) {
  __shared__ uint32_t h[2048];
  for (int t = threadIdx.x; t < 2048; t += 256) h[t] = hist[t];
  __syncthreads();
  if (threadIdx.x != 0) return;
  uint32_t total_pos = 0, total_neg = 0;
  for (int b = 0; b < 1024; ++b) total_pos += h[b];
  for (int b = 0; b < 1024; ++b) total_neg += h[1024 + b];
  int pos_kept = total_pos < (uint32_t)NPOS_TGT ? (int)total_pos : NPOS_TGT;
  int n_neg = NSAMPLE - pos_kept;
  sc->pos_kept = pos_kept;
  if (total_pos <= (uint32_t)NPOS_TGT) {
    sc->do_pos = 0; sc->cutoff[0] = ~0ull;
  } else {
    uint32_t cum = 0; int B = 0;
    for (; B < 1024; ++B) { if (cum + h[B] > (uint32_t)NPOS_TGT) break; cum += h[B]; }
    sc->do_pos = 1; sc->B_pos = B; sc->r_pos = NPOS_TGT - (int)cum;
  }
  if (total_neg <= (uint32_t)n_neg) {
    sc->do_neg = 0; sc->cutoff[1] = ~0ull;
  } else {
    uint32_t cum = 0; int B = 0;
    for (; B < 1024; ++B) { if (cum + h[1024 + B] > (uint32_t)n_neg) break; cum += h[1024 + B]; }
    sc->do_neg = 1; sc->B_neg = B; sc->r_neg = n_neg - (int)cum;
  }
}

// K6: collect boundary-bucket members
__global__ __launch_bounds__(256) void k_collect(const int* __restrict__ label,
                                                 uint64_t* __restrict__ pos_list,
                                                 uint64_t* __restrict__ neg_list,
                                                 uint32_t* __restrict__ counters,
                                                 const ScalarBlk* __restrict__ sc) {
  int i = blockIdx.x * 256 + threadIdx.x;
  int lbl = label[i];
  if (lbl < 0) return;
  if (lbl == 1) {
    if (!sc->do_pos) return;
    float p = p_from_bits(rbits(KPOS, (uint32_t)i));
    int b = (int)(p * 1024.0f); if (b > 1023) b = 1023;
    if (b != sc->B_pos) return;
    uint32_t slot = atomicAdd((unsigned int*)&counters[0], 1u);
    if (slot < POS_CAP) pos_list[slot] = prio_key(p, (uint32_t)i);
  } else {
    if (!sc->do_neg) return;
    float p = p_from_bits(rbits(KNEG, (uint32_t)i));
    int b = (int)(p * 1024.0f); if (b > 1023) b = 1023;
    if (b != sc->B_neg) return;
    uint32_t slot = atomicAdd((unsigned int*)&counters[1], 1u);
    if (slot < NEG_CAP) neg_list[slot] = prio_key(p, (uint32_t)i);
  }
}

// K7: exact r-th smallest key within boundary bucket -> cutoff
__global__ __launch_bounds__(256) void k_cutoff(const uint64_t* __restrict__ pos_list,
                                                const uint64_t* __restrict__ neg_list,
                                                const uint32_t* __restrict__ counters,
                                                ScalarBlk* __restrict__ sc) {
  int cls = blockIdx.x;
  int doit = (cls == 0) ? sc->do_pos : sc->do_neg;
  if (!doit) return;
  const uint64_t* list = (cls == 0) ? pos_list : neg_list;
  int cap = (cls == 0) ? POS_CAP : NEG_CAP;
  int m = (int)counters[cls]; if (m > cap) m = cap;
  int r = (cls == 0) ? sc->r_pos : sc->r_neg;
  for (int j = threadIdx.x; j < m; j += 256) {
    uint64_t kj = list[j];
    int rank = 0;
    for (int t = 0; t < m; ++t) rank += (list[t] < kj) ? 1 : 0;
    if (rank == r) sc->cutoff[cls] = (unsigned long long)kj;
  }
}

// K8: final labels + bbox2loc
__global__ __launch_bounds__(256) void k_final(const float4* __restrict__ anchor,
                                               const float4* __restrict__ bbox,
                                               const int* __restrict__ argmax,
                                               const int* __restrict__ label,
                                               const ScalarBlk* __restrict__ sc,
                                               float* __restrict__ out) {
  #pragma clang fp contract(off)
  int i = blockIdx.x * 256 + threadIdx.x;
  int lbl = label[i];
  if (lbl == 1) {
    float p = p_from_bits(rbits(KPOS, (uint32_t)i));
    if (prio_key(p, (uint32_t)i) >= sc->cutoff[0]) lbl = -1;
  } else if (lbl == 0) {
    float p = p_from_bits(rbits(KNEG, (uint32_t)i));
    if (prio_key(p, (uint32_t)i) >= sc->cutoff[1]) lbl = -1;
  }
  out[K_ANCH * 4 + i] = (float)lbl;

  float4 a = anchor[i];
  float4 b = bbox[argmax[i]];
  const float eps = 1.1920928955078125e-07f;
  float w  = fmaxf(a.z - a.x, eps);
  float h  = fmaxf(a.w - a.y, eps);
  float cx = a.x + 0.5f * (a.z - a.x);
  float cy = a.y + 0.5f * (a.w - a.y);
  float bw = b.z - b.x, bh = b.w - b.y;
  float bcx = b.x + 0.5f * bw, bcy = b.y + 0.5f * bh;
  float dx = (bcx - cx) / w, dy = (bcy - cy) / h;
  float dw = logf(bw / w), dh = logf(bh / h);
  float4 o;
  if (sc->pos_kept > 0) o = make_float4(dx, dy, dw, dh);
  else o = make_float4(0.f, 0.f, 0.f, 0.f);
  ((float4*)out)[i] = o;
}

extern "C" void kernel_launch(void* const* d_in, const int* in_sizes, int n_in,
                              void* d_out, int out_size, void* d_ws, size_t ws_size,
                              hipStream_t stream) {
  const float4* anchor = (const float4*)d_in[0];
  const float4* bbox   = (const float4*)d_in[1];
  char* ws = (char*)d_ws;

  uint32_t* hist     = (uint32_t*)(ws);                   // [0, 8192)
  uint32_t* counters = (uint32_t*)(ws + 8192);            // [8192, 8200)
  unsigned long long* gkey_part = (unsigned long long*)(ws + 16384);  // 32 KB: [16384, 49152)
  ScalarBlk* sc      = (ScalarBlk*)(ws + 49152);
  int* argmax        = (int*)(ws + 65536);                // 512 KB
  int* label         = (int*)(ws + 65536 + 524288);       // 512 KB
  uint64_t* pos_list = (uint64_t*)(ws + 65536 + 1048576);
  uint64_t* neg_list = pos_list + POS_CAP;

  (void)hipMemsetAsync(ws, 0, 49152, stream);  // hist + counters + gkey_part
  k_fused  <<<2048, 256, 0, stream>>>(anchor, bbox, argmax, label, gkey_part);
  k_force  <<<1,    256, 0, stream>>>(gkey_part, argmax, label);
  k_hist   <<<512,  256, 0, stream>>>(label, hist);
  k_select <<<1,    256, 0, stream>>>(hist, sc);
  k_collect<<<512,  256, 0, stream>>>(label, pos_list, neg_list, counters, sc);
  k_cutoff <<<2,    256, 0, stream>>>(pos_list, neg_list, counters, sc);
  k_final  <<<512,  256, 0, stream>>>(anchor, bbox, argmax, label, sc, (float*)d_out);
}